// Round 1
// baseline (1310.155 us; speedup 1.0000x reference)
//
#include <hip/hip_runtime.h>
#include <hip/hip_bf16.h>

// Problem constants
#define Bsz 4
#define Tsz 2048
#define Dsz 1024
#define Ssz 16
#define Esz 2048
#define Mrows (Bsz*Tsz)        // 8192

typedef __attribute__((ext_vector_type(8))) short short8;
typedef __attribute__((ext_vector_type(4))) float floatx4;

__device__ __forceinline__ void async_ld16(const void* g, void* l) {
    __builtin_amdgcn_global_load_lds(
        (const __attribute__((address_space(1))) void*)g,
        (__attribute__((address_space(3))) void*)l,
        16, 0, 0);
}

__device__ __forceinline__ float sigmoidf_(float v) { return 1.f / (1.f + expf(-v)); }

// ---------------------------------------------------------------------------
// fp32 -> bf16 conversion (grid-stride)
// ---------------------------------------------------------------------------
__global__ void f32_to_bf16(const float* __restrict__ in, __hip_bfloat16* __restrict__ out, int n) {
    int i = blockIdx.x * blockDim.x + threadIdx.x;
    int stride = gridDim.x * blockDim.x;
    for (; i < n; i += stride) out[i] = __float2bfloat16(in[i]);
}

// ---------------------------------------------------------------------------
// bf16 GEMM: C[M,N] = A[M,K] @ Bw[N,K]^T (+bias), 128x128 tile, 4 waves,
// each wave 64x64 via 4x4 mfma_f32_16x16x32_bf16.  MODE:
//   0: store bf16(out + bias)                  -> outb
//   1: softplus(out + bias), row-sum, atomic   -> rowsum
//   2: fp32 out + bias + resid                 -> outf
// ---------------------------------------------------------------------------
template<int MODE>
__launch_bounds__(256)
__global__ void gemm_bt(const __hip_bfloat16* __restrict__ A,
                        const __hip_bfloat16* __restrict__ Bw,
                        const float* __restrict__ bias,
                        int M, int N, int K,
                        __hip_bfloat16* __restrict__ outb,
                        float* __restrict__ rowsum,
                        const float* __restrict__ resid,
                        float* __restrict__ outf) {
    __shared__ __align__(16) __hip_bfloat16 sA[128 * 32];
    __shared__ __align__(16) __hip_bfloat16 sB[128 * 32];

    const int tid  = threadIdx.x;
    const int wave = tid >> 6, lane = tid & 63;
    const int wm = wave >> 1, wn = wave & 1;
    const int q = lane >> 4, lr = lane & 15;
    const int m0 = blockIdx.y * 128, n0 = blockIdx.x * 128;

    floatx4 acc[4][4];
#pragma unroll
    for (int i = 0; i < 4; ++i)
#pragma unroll
        for (int j = 0; j < 4; ++j) acc[i][j] = (floatx4){0.f, 0.f, 0.f, 0.f};

    // staging: tile is 128 rows x 32 cols bf16 = 8192B = 512 x 16B chunks.
    // 256 threads x 2 issues each; LDS dest base is wave-uniform, lane*16 implicit.
    const int c0 = (wave * 2 + 0) * 64 + lane;   // chunk id, issue 0
    const int c1 = (wave * 2 + 1) * 64 + lane;   // chunk id, issue 1
    const int ra0 = c0 >> 2, ca0 = (c0 & 3) * 8;
    const int ra1 = c1 >> 2, ca1 = (c1 & 3) * 8;

    const int nkt = K >> 5;
    for (int kt = 0; kt < nkt; ++kt) {
        const int k0 = kt << 5;
        __syncthreads();
        async_ld16(&A [(size_t)(m0 + ra0) * K + k0 + ca0], &sA[(wave * 2 + 0) * 512]);
        async_ld16(&A [(size_t)(m0 + ra1) * K + k0 + ca1], &sA[(wave * 2 + 1) * 512]);
        async_ld16(&Bw[(size_t)(n0 + ra0) * K + k0 + ca0], &sB[(wave * 2 + 0) * 512]);
        async_ld16(&Bw[(size_t)(n0 + ra1) * K + k0 + ca1], &sB[(wave * 2 + 1) * 512]);
        __syncthreads();

        short8 af[4], bfr[4];
#pragma unroll
        for (int i = 0; i < 4; ++i)
            af[i] = *(const short8*)&sA[(wm * 64 + i * 16 + lr) * 32 + q * 8];
#pragma unroll
        for (int j = 0; j < 4; ++j)
            bfr[j] = *(const short8*)&sB[(wn * 64 + j * 16 + lr) * 32 + q * 8];
#pragma unroll
        for (int i = 0; i < 4; ++i)
#pragma unroll
            for (int j = 0; j < 4; ++j)
                acc[i][j] = __builtin_amdgcn_mfma_f32_16x16x32_bf16(af[i], bfr[j], acc[i][j], 0, 0, 0);
    }

    // epilogue: C/D layout col = lane&15, row = (lane>>4)*4 + reg
    if (MODE == 0) {
#pragma unroll
        for (int i = 0; i < 4; ++i) {
            const int row = m0 + wm * 64 + i * 16 + q * 4;
#pragma unroll
            for (int j = 0; j < 4; ++j) {
                const int col = n0 + wn * 64 + j * 16 + lr;
                const float bc = bias[col];
#pragma unroll
                for (int r = 0; r < 4; ++r)
                    outb[(size_t)(row + r) * N + col] = __float2bfloat16(acc[i][j][r] + bc);
            }
        }
    } else if (MODE == 1) {
#pragma unroll
        for (int i = 0; i < 4; ++i) {
            float rs[4] = {0.f, 0.f, 0.f, 0.f};
#pragma unroll
            for (int j = 0; j < 4; ++j) {
                const int col = n0 + wn * 64 + j * 16 + lr;
                const float bc = bias[col];
#pragma unroll
                for (int r = 0; r < 4; ++r) {
                    float v = acc[i][j][r] + bc;
                    float sp = (v > 20.f) ? v : log1pf(expf(v));
                    rs[r] += sp;
                }
            }
#pragma unroll
            for (int r = 0; r < 4; ++r) {
                float v = rs[r];
                v += __shfl_xor(v, 1); v += __shfl_xor(v, 2);
                v += __shfl_xor(v, 4); v += __shfl_xor(v, 8);
                if (lr == 0)
                    atomicAdd(&rowsum[m0 + wm * 64 + i * 16 + q * 4 + r], v);
            }
        }
    } else {
#pragma unroll
        for (int i = 0; i < 4; ++i) {
            const int row = m0 + wm * 64 + i * 16 + q * 4;
#pragma unroll
            for (int j = 0; j < 4; ++j) {
                const int col = n0 + wn * 64 + j * 16 + lr;
                const float bc = bias[col];
#pragma unroll
                for (int r = 0; r < 4; ++r) {
                    const size_t idx = (size_t)(row + r) * N + col;
                    outf[idx] = acc[i][j][r] + bc + resid[idx];
                }
            }
        }
    }
}

// ---------------------------------------------------------------------------
// depthwise conv (k=3, pad 1, along T) + bias + SiLU.  xp is [M, 2E] bf16,
// main half = cols [0,E).  Writes xc [M, E] bf16.
// ---------------------------------------------------------------------------
__global__ void conv_silu_k(const __hip_bfloat16* __restrict__ xp,
                            const float* __restrict__ cw,
                            const float* __restrict__ cb,
                            __hip_bfloat16* __restrict__ xc) {
    const int idx = blockIdx.x * blockDim.x + threadIdx.x;
    if (idx >= Mrows * Esz) return;
    const int e = idx & (Esz - 1);
    const int r = idx >> 11;        // E = 2048 = 2^11
    const int t = r & (Tsz - 1);    // T = 2048
    const size_t base = (size_t)r * (2 * Esz) + e;
    const float xm1 = (t > 0)       ? __bfloat162float(xp[base - 2 * Esz]) : 0.f;
    const float x00 = __bfloat162float(xp[base]);
    const float xp1 = (t < Tsz - 1) ? __bfloat162float(xp[base + 2 * Esz]) : 0.f;
    float v = xm1 * cw[e * 3 + 0] + x00 * cw[e * 3 + 1] + xp1 * cw[e * 3 + 2] + cb[e];
    xc[idx] = __float2bfloat16(v * sigmoidf_(v));
}

// ---------------------------------------------------------------------------
// decay[r] = exp(clip(-rowsum[r]/E, -10, 10))
// ---------------------------------------------------------------------------
__global__ void decay_k(const float* __restrict__ rowsum, float* __restrict__ dec) {
    const int r = blockIdx.x * blockDim.x + threadIdx.x;
    if (r < Mrows) {
        const float m = rowsum[r] * (1.f / (float)Esz);
        const float c = fminf(fmaxf(-m, -10.f), 10.f);
        dec[r] = expf(c);
    }
}

// ---------------------------------------------------------------------------
// Bt/Ct/Dt projections (S=16 each, K=E) + u = Bt*Dt.  One row per block.
// threads 0-15: B, 16-31: C, 32-47: D.
// ---------------------------------------------------------------------------
__global__ void bcd_k(const __hip_bfloat16* __restrict__ xc,
                      const float* __restrict__ Bw, const float* __restrict__ Bb,
                      const float* __restrict__ Cw, const float* __restrict__ Cb,
                      const float* __restrict__ Dw, const float* __restrict__ Db,
                      float* __restrict__ u, float* __restrict__ Ct) {
    const int r = blockIdx.x;
    const int tid = threadIdx.x;  // 64
    __shared__ float bres[Ssz], dres[Ssz];
    const int g = tid >> 4, s = tid & 15;
    if (g < 3) {
        const float* W = (g == 0) ? Bw : (g == 1) ? Cw : Dw;
        const __hip_bfloat16* xr = xc + (size_t)r * Esz;
        const float* wr = W + s * Esz;
        float acc = 0.f;
#pragma unroll 4
        for (int k = 0; k < Esz; k += 2) {
            acc += __bfloat162float(xr[k]) * wr[k] + __bfloat162float(xr[k + 1]) * wr[k + 1];
        }
        if (g == 0)      bres[s] = acc + Bb[s];
        else if (g == 1) Ct[(size_t)r * Ssz + s] = acc + Cb[s];
        else             dres[s] = acc + Db[s];
    }
    __syncthreads();
    if (tid < Ssz) u[(size_t)r * Ssz + tid] = bres[tid] * dres[tid];
}

// ---------------------------------------------------------------------------
// Sequential SSM scan.  One block per batch (4 blocks, 256 threads),
// chunks of 256 timesteps staged through LDS; lanes 0-15 of wave 0 carry the
// state (one lane per s).
// ---------------------------------------------------------------------------
__global__ void scan_k(const float* __restrict__ dec, const float* __restrict__ u,
                       const float* __restrict__ Ct, float* __restrict__ ys) {
    const int b = blockIdx.x;
    const int tid = threadIdx.x;
    const int lane = tid & 63, wave = tid >> 6;
    __shared__ __align__(16) float su[256 * Ssz];
    __shared__ __align__(16) float sc[256 * Ssz];
    __shared__ float sd[256];
    __shared__ float sy[256];
    float st = 0.f;
    for (int t0 = 0; t0 < Tsz; t0 += 256) {
        __syncthreads();
        const float4* ub = (const float4*)(u  + ((size_t)b * Tsz + t0) * Ssz);
        const float4* cb = (const float4*)(Ct + ((size_t)b * Tsz + t0) * Ssz);
#pragma unroll
        for (int i = 0; i < 4; ++i) {
            ((float4*)su)[tid + i * 256] = ub[tid + i * 256];
            ((float4*)sc)[tid + i * 256] = cb[tid + i * 256];
        }
        sd[tid] = dec[b * Tsz + t0 + tid];
        __syncthreads();
        if (wave == 0 && lane < 16) {
            for (int i = 0; i < 256; ++i) {
                const float d = sd[i];
                st = st * d + su[i * Ssz + lane];
                float p = sc[i * Ssz + lane] * st;
                p += __shfl_xor(p, 1); p += __shfl_xor(p, 2);
                p += __shfl_xor(p, 4); p += __shfl_xor(p, 8);
                if (lane == 0) sy[i] = p;
            }
        }
        __syncthreads();
        ys[b * Tsz + t0 + tid] = sy[tid];
    }
}

// ---------------------------------------------------------------------------
// y[r,e] = ys[r] * silu(x_gate[r,e]);  x_gate = xp cols [E, 2E).  bf16 out.
// ---------------------------------------------------------------------------
__global__ void ygate_k(const float* __restrict__ ys, const __hip_bfloat16* __restrict__ xp,
                        __hip_bfloat16* __restrict__ y) {
    const int idx = blockIdx.x * blockDim.x + threadIdx.x;
    if (idx >= Mrows * Esz) return;
    const int e = idx & (Esz - 1);
    const size_t r = (size_t)(idx >> 11);
    const float g = __bfloat162float(xp[r * (2 * Esz) + Esz + e]);
    y[idx] = __float2bfloat16(ys[r] * g * sigmoidf_(g));
}

// ---------------------------------------------------------------------------
extern "C" void kernel_launch(void* const* d_in, const int* in_sizes, int n_in,
                              void* d_out, int out_size, void* d_ws, size_t ws_size,
                              hipStream_t stream) {
    const float* x      = (const float*)d_in[0];
    const float* in_w   = (const float*)d_in[1];
    const float* in_b   = (const float*)d_in[2];
    const float* conv_w = (const float*)d_in[3];
    const float* conv_b = (const float*)d_in[4];
    const float* dt_w   = (const float*)d_in[5];
    const float* dt_b   = (const float*)d_in[6];
    const float* B_w    = (const float*)d_in[7];
    const float* B_b    = (const float*)d_in[8];
    const float* C_w    = (const float*)d_in[9];
    const float* C_b    = (const float*)d_in[10];
    const float* D_w    = (const float*)d_in[11];
    const float* D_b    = (const float*)d_in[12];
    const float* out_w  = (const float*)d_in[13];
    const float* out_b  = (const float*)d_in[14];
    float* out = (float*)d_out;

    char* ws = (char*)d_ws;
    auto alloc = [&](size_t bytes) {
        char* p = ws;
        ws += (bytes + 255) & ~(size_t)255;
        return p;
    };
    __hip_bfloat16* x_bf    = (__hip_bfloat16*)alloc((size_t)Mrows * Dsz * 2);       // 16 MB
    __hip_bfloat16* inw_bf  = (__hip_bfloat16*)alloc((size_t)2 * Esz * Dsz * 2);     //  8 MB
    __hip_bfloat16* dtw_bf  = (__hip_bfloat16*)alloc((size_t)Esz * Esz * 2);         //  8 MB
    __hip_bfloat16* outw_bf = (__hip_bfloat16*)alloc((size_t)Dsz * Esz * 2);         //  4 MB
    __hip_bfloat16* xp_bf   = (__hip_bfloat16*)alloc((size_t)Mrows * 2 * Esz * 2);   // 64 MB
    __hip_bfloat16* xc_bf   = (__hip_bfloat16*)alloc((size_t)Mrows * Esz * 2);       // 32 MB
    float* rowsum = (float*)alloc(Mrows * 4);
    float* dec    = (float*)alloc(Mrows * 4);
    float* u_buf  = (float*)alloc((size_t)Mrows * Ssz * 4);
    float* ct_buf = (float*)alloc((size_t)Mrows * Ssz * 4);
    float* ys_buf = (float*)alloc(Mrows * 4);
    __hip_bfloat16* y_bf = xc_bf;   // reuse: xc dead after bcd_k/gemm<1>

    hipMemsetAsync(rowsum, 0, Mrows * 4, stream);

    // conversions
    f32_to_bf16<<<4096, 256, 0, stream>>>(x,     x_bf,    Mrows * Dsz);
    f32_to_bf16<<<4096, 256, 0, stream>>>(in_w,  inw_bf,  2 * Esz * Dsz);
    f32_to_bf16<<<4096, 256, 0, stream>>>(dt_w,  dtw_bf,  Esz * Esz);
    f32_to_bf16<<<4096, 256, 0, stream>>>(out_w, outw_bf, Dsz * Esz);

    // GEMM1: xp = x @ in_w^T + in_b  (M=8192, N=4096, K=1024) -> bf16
    gemm_bt<0><<<dim3(4096 / 128, Mrows / 128), 256, 0, stream>>>(
        x_bf, inw_bf, in_b, Mrows, 4096, 1024, xp_bf, nullptr, nullptr, nullptr);

    // conv + SiLU -> xc
    conv_silu_k<<<(Mrows * Esz) / 256, 256, 0, stream>>>(xp_bf, conv_w, conv_b, xc_bf);

    // GEMM2: softplus(xc @ dt_w^T + dt_b) row-sums (M=8192, N=2048, K=2048)
    gemm_bt<1><<<dim3(Esz / 128, Mrows / 128), 256, 0, stream>>>(
        xc_bf, dtw_bf, dt_b, Mrows, Esz, Esz, nullptr, rowsum, nullptr, nullptr);

    decay_k<<<Mrows / 256, 256, 0, stream>>>(rowsum, dec);

    // B/C/D projections + u = Bt*Dt
    bcd_k<<<Mrows, 64, 0, stream>>>(xc_bf, B_w, B_b, C_w, C_b, D_w, D_b, u_buf, ct_buf);

    // sequential scan -> ys
    scan_k<<<Bsz, 256, 0, stream>>>(dec, u_buf, ct_buf, ys_buf);

    // y = ys * silu(x_gate) -> bf16 (into xc buffer)
    ygate_k<<<(Mrows * Esz) / 256, 256, 0, stream>>>(ys_buf, xp_bf, y_bf);

    // GEMM3: out = x + y @ out_w^T + out_b  (M=8192, N=1024, K=2048) -> fp32
    gemm_bt<2><<<dim3(Dsz / 128, Mrows / 128), 256, 0, stream>>>(
        y_bf, outw_bf, out_b, Mrows, Dsz, Esz, nullptr, nullptr, x, out);
}

// Round 2
// 593.455 us; speedup vs baseline: 2.2077x; 2.2077x over previous
//
#include <hip/hip_runtime.h>
#include <hip/hip_bf16.h>

// Problem constants
#define Bsz 4
#define Tsz 2048
#define Dsz 1024
#define Ssz 16
#define Esz 2048
#define Mrows (Bsz*Tsz)        // 8192

typedef __attribute__((ext_vector_type(8))) short short8;
typedef __attribute__((ext_vector_type(4))) float floatx4;

__device__ __forceinline__ void async_ld16(const void* g, void* l) {
    __builtin_amdgcn_global_load_lds(
        (const __attribute__((address_space(1))) void*)g,
        (__attribute__((address_space(3))) void*)l,
        16, 0, 0);
}

__device__ __forceinline__ float sigmoidf_(float v) { return 1.f / (1.f + expf(-v)); }

// ---------------------------------------------------------------------------
// fp32 -> bf16 conversion, vectorized (float4 -> ushort4)
// ---------------------------------------------------------------------------
__global__ void f32_to_bf16v(const float4* __restrict__ in, ushort4* __restrict__ out, int n4) {
    int i = blockIdx.x * blockDim.x + threadIdx.x;
    int stride = gridDim.x * blockDim.x;
    for (; i < n4; i += stride) {
        float4 v = in[i];
        __hip_bfloat16 a = __float2bfloat16(v.x), b = __float2bfloat16(v.y);
        __hip_bfloat16 c = __float2bfloat16(v.z), d = __float2bfloat16(v.w);
        ushort4 o;
        o.x = *(unsigned short*)&a; o.y = *(unsigned short*)&b;
        o.z = *(unsigned short*)&c; o.w = *(unsigned short*)&d;
        out[i] = o;
    }
}

// ---------------------------------------------------------------------------
// bf16 GEMM: C[M,N] = A[M,K] @ Bw[N,K]^T (+bias), 128x128 tile, 4 waves,
// each wave 64x64 via 4x4 mfma_f32_16x16x32_bf16.  MODE:
//   0: store bf16(out + bias)                  -> outb
//   1: softplus(out + bias), row-sum, atomic   -> rowsum
//   2: fp32 out + bias + resid                 -> outf
// ---------------------------------------------------------------------------
template<int MODE>
__launch_bounds__(256)
__global__ void gemm_bt(const __hip_bfloat16* __restrict__ A,
                        const __hip_bfloat16* __restrict__ Bw,
                        const float* __restrict__ bias,
                        int M, int N, int K,
                        __hip_bfloat16* __restrict__ outb,
                        float* __restrict__ rowsum,
                        const float* __restrict__ resid,
                        float* __restrict__ outf) {
    __shared__ __align__(16) __hip_bfloat16 sA[128 * 32];
    __shared__ __align__(16) __hip_bfloat16 sB[128 * 32];

    const int tid  = threadIdx.x;
    const int wave = tid >> 6, lane = tid & 63;
    const int wm = wave >> 1, wn = wave & 1;
    const int q = lane >> 4, lr = lane & 15;
    const int m0 = blockIdx.y * 128, n0 = blockIdx.x * 128;

    floatx4 acc[4][4];
#pragma unroll
    for (int i = 0; i < 4; ++i)
#pragma unroll
        for (int j = 0; j < 4; ++j) acc[i][j] = (floatx4){0.f, 0.f, 0.f, 0.f};

    const int c0 = (wave * 2 + 0) * 64 + lane;
    const int c1 = (wave * 2 + 1) * 64 + lane;
    const int ra0 = c0 >> 2, ca0 = (c0 & 3) * 8;
    const int ra1 = c1 >> 2, ca1 = (c1 & 3) * 8;

    const int nkt = K >> 5;
    for (int kt = 0; kt < nkt; ++kt) {
        const int k0 = kt << 5;
        __syncthreads();
        async_ld16(&A [(size_t)(m0 + ra0) * K + k0 + ca0], &sA[(wave * 2 + 0) * 512]);
        async_ld16(&A [(size_t)(m0 + ra1) * K + k0 + ca1], &sA[(wave * 2 + 1) * 512]);
        async_ld16(&Bw[(size_t)(n0 + ra0) * K + k0 + ca0], &sB[(wave * 2 + 0) * 512]);
        async_ld16(&Bw[(size_t)(n0 + ra1) * K + k0 + ca1], &sB[(wave * 2 + 1) * 512]);
        __syncthreads();

        short8 af[4], bfr[4];
#pragma unroll
        for (int i = 0; i < 4; ++i)
            af[i] = *(const short8*)&sA[(wm * 64 + i * 16 + lr) * 32 + q * 8];
#pragma unroll
        for (int j = 0; j < 4; ++j)
            bfr[j] = *(const short8*)&sB[(wn * 64 + j * 16 + lr) * 32 + q * 8];
#pragma unroll
        for (int i = 0; i < 4; ++i)
#pragma unroll
            for (int j = 0; j < 4; ++j)
                acc[i][j] = __builtin_amdgcn_mfma_f32_16x16x32_bf16(af[i], bfr[j], acc[i][j], 0, 0, 0);
    }

    // epilogue: C/D layout col = lane&15, row = (lane>>4)*4 + reg
    if (MODE == 0) {
#pragma unroll
        for (int i = 0; i < 4; ++i) {
            const int row = m0 + wm * 64 + i * 16 + q * 4;
#pragma unroll
            for (int j = 0; j < 4; ++j) {
                const int col = n0 + wn * 64 + j * 16 + lr;
                const float bc = bias[col];
#pragma unroll
                for (int r = 0; r < 4; ++r)
                    outb[(size_t)(row + r) * N + col] = __float2bfloat16(acc[i][j][r] + bc);
            }
        }
    } else if (MODE == 1) {
#pragma unroll
        for (int i = 0; i < 4; ++i) {
            float rs[4] = {0.f, 0.f, 0.f, 0.f};
#pragma unroll
            for (int j = 0; j < 4; ++j) {
                const int col = n0 + wn * 64 + j * 16 + lr;
                const float bc = bias[col];
#pragma unroll
                for (int r = 0; r < 4; ++r) {
                    float v = acc[i][j][r] + bc;
                    float sp = (v > 20.f) ? v : log1pf(expf(v));
                    rs[r] += sp;
                }
            }
#pragma unroll
            for (int r = 0; r < 4; ++r) {
                float v = rs[r];
                v += __shfl_xor(v, 1); v += __shfl_xor(v, 2);
                v += __shfl_xor(v, 4); v += __shfl_xor(v, 8);
                if (lr == 0)
                    atomicAdd(&rowsum[m0 + wm * 64 + i * 16 + q * 4 + r], v);
            }
        }
    } else {
#pragma unroll
        for (int i = 0; i < 4; ++i) {
            const int row = m0 + wm * 64 + i * 16 + q * 4;
#pragma unroll
            for (int j = 0; j < 4; ++j) {
                const int col = n0 + wn * 64 + j * 16 + lr;
                const float bc = bias[col];
#pragma unroll
                for (int r = 0; r < 4; ++r) {
                    const size_t idx = (size_t)(row + r) * N + col;
                    outf[idx] = acc[i][j][r] + bc + resid[idx];
                }
            }
        }
    }
}

// ---------------------------------------------------------------------------
// depthwise conv (k=3, pad 1, along T) + bias + SiLU.
// ---------------------------------------------------------------------------
__global__ void conv_silu_k(const __hip_bfloat16* __restrict__ xp,
                            const float* __restrict__ cw,
                            const float* __restrict__ cb,
                            __hip_bfloat16* __restrict__ xc) {
    const int idx = blockIdx.x * blockDim.x + threadIdx.x;
    if (idx >= Mrows * Esz) return;
    const int e = idx & (Esz - 1);
    const int r = idx >> 11;
    const int t = r & (Tsz - 1);
    const size_t base = (size_t)r * (2 * Esz) + e;
    const float xm1 = (t > 0)       ? __bfloat162float(xp[base - 2 * Esz]) : 0.f;
    const float x00 = __bfloat162float(xp[base]);
    const float xp1 = (t < Tsz - 1) ? __bfloat162float(xp[base + 2 * Esz]) : 0.f;
    float v = xm1 * cw[e * 3 + 0] + x00 * cw[e * 3 + 1] + xp1 * cw[e * 3 + 2] + cb[e];
    xc[idx] = __float2bfloat16(v * sigmoidf_(v));
}

// ---------------------------------------------------------------------------
// decay[r] = exp(clip(-rowsum[r]/E, -10, 10))
// ---------------------------------------------------------------------------
__global__ void decay_k(const float* __restrict__ rowsum, float* __restrict__ dec) {
    const int r = blockIdx.x * blockDim.x + threadIdx.x;
    if (r < Mrows) {
        const float m = rowsum[r] * (1.f / (float)Esz);
        const float c = fminf(fmaxf(-m, -10.f), 10.f);
        dec[r] = expf(c);
    }
}

// ---------------------------------------------------------------------------
// pack B_w/C_w/D_w (each [16,2048] fp32) into Wb [48,2048] bf16
// ---------------------------------------------------------------------------
__global__ void pack_bcd(const float* __restrict__ Bw, const float* __restrict__ Cw,
                         const float* __restrict__ Dw, __hip_bfloat16* __restrict__ Wb) {
    const int idx = blockIdx.x * blockDim.x + threadIdx.x;
    if (idx >= 48 * Esz) return;
    const int row = idx >> 11, col = idx & (Esz - 1);
    float v;
    if (row < 16)      v = Bw[row * Esz + col];
    else if (row < 32) v = Cw[(row - 16) * Esz + col];
    else               v = Dw[(row - 32) * Esz + col];
    Wb[idx] = __float2bfloat16(v);
}

// ---------------------------------------------------------------------------
// B/C/D projections via MFMA skinny GEMM: xc[M,E] @ Wb[48,E]^T.
// 64-row tile per block, 4 waves x 16 rows, 3 col-tiles (B,C,D).
// Epilogue: u = (Bt+bb)*(Dt+db), Ct stored.  j=0 and j=2 live in same lane.
// ---------------------------------------------------------------------------
__launch_bounds__(256)
__global__ void bcd_mfma(const __hip_bfloat16* __restrict__ xc,
                         const __hip_bfloat16* __restrict__ Wb,
                         const float* __restrict__ Bb, const float* __restrict__ Cb,
                         const float* __restrict__ Db,
                         float* __restrict__ u, float* __restrict__ Ct) {
    __shared__ __align__(16) __hip_bfloat16 sA[64 * 32];   // 4 KB
    __shared__ __align__(16) __hip_bfloat16 sW[48 * 32];   // 3 KB
    const int tid = threadIdx.x;
    const int wave = tid >> 6, lane = tid & 63;
    const int q = lane >> 4, lr = lane & 15;
    const int m0 = blockIdx.x * 64;

    floatx4 acc[3];
#pragma unroll
    for (int j = 0; j < 3; ++j) acc[j] = (floatx4){0.f, 0.f, 0.f, 0.f};

    const int ra = wave * 16 + (lane >> 2);   // A-tile row this lane stages
    const int ca = (lane & 3) * 8;            // col offset (bf16)
    const int rw = wave * 16 + (lane >> 2);   // W-tile row (waves 0-2)

    for (int kt = 0; kt < (Esz >> 5); ++kt) {
        const int k0 = kt << 5;
        __syncthreads();
        async_ld16(&xc[(size_t)(m0 + ra) * Esz + k0 + ca], &sA[wave * 512]);
        if (wave < 3)
            async_ld16(&Wb[(size_t)rw * Esz + k0 + ca], &sW[wave * 512]);
        __syncthreads();

        short8 af = *(const short8*)&sA[(wave * 16 + lr) * 32 + q * 8];
#pragma unroll
        for (int j = 0; j < 3; ++j) {
            short8 wf = *(const short8*)&sW[(j * 16 + lr) * 32 + q * 8];
            acc[j] = __builtin_amdgcn_mfma_f32_16x16x32_bf16(af, wf, acc[j], 0, 0, 0);
        }
    }

    const int row = m0 + wave * 16 + q * 4;
    const float bb = Bb[lr], cbv = Cb[lr], db = Db[lr];
#pragma unroll
    for (int r = 0; r < 4; ++r) {
        const float bt = acc[0][r] + bb;
        const float ct = acc[1][r] + cbv;
        const float dt = acc[2][r] + db;
        u [(size_t)(row + r) * Ssz + lr] = bt * dt;
        Ct[(size_t)(row + r) * Ssz + lr] = ct;
    }
}

// ---------------------------------------------------------------------------
// Sequential SSM scan.  One block per batch.  Wave 0 lanes 0-15 carry state;
// the cross-s reduction is moved OFF the serial chain: products go to LDS,
// then all 256 threads reduce 16-wide sums in parallel.
// ---------------------------------------------------------------------------
__global__ void scan_k(const float* __restrict__ dec, const float* __restrict__ u,
                       const float* __restrict__ Ct, float* __restrict__ ys) {
    const int b = blockIdx.x;
    const int tid = threadIdx.x;
    const int lane = tid & 63, wave = tid >> 6;
    __shared__ __align__(16) float su[256 * Ssz];   // 16 KB
    __shared__ __align__(16) float sc[256 * Ssz];   // 16 KB
    __shared__ float sp[256 * 17];                  // 17 KB, padded stride
    __shared__ float sd[256];
    float st = 0.f;
    for (int t0 = 0; t0 < Tsz; t0 += 256) {
        __syncthreads();
        const float4* ub = (const float4*)(u  + ((size_t)b * Tsz + t0) * Ssz);
        const float4* cb = (const float4*)(Ct + ((size_t)b * Tsz + t0) * Ssz);
#pragma unroll
        for (int i = 0; i < 4; ++i) {
            ((float4*)su)[tid + i * 256] = ub[tid + i * 256];
            ((float4*)sc)[tid + i * 256] = cb[tid + i * 256];
        }
        sd[tid] = dec[b * Tsz + t0 + tid];
        __syncthreads();
        if (wave == 0 && lane < 16) {
#pragma unroll 8
            for (int i = 0; i < 256; ++i) {
                st = st * sd[i] + su[i * Ssz + lane];
                sp[i * 17 + lane] = sc[i * Ssz + lane] * st;
            }
        }
        __syncthreads();
        float s = 0.f;
#pragma unroll
        for (int j = 0; j < 16; ++j) s += sp[tid * 17 + j];
        ys[b * Tsz + t0 + tid] = s;
    }
}

// ---------------------------------------------------------------------------
// y[r,e] = ys[r] * silu(x_gate[r,e]);  x_gate = xp cols [E, 2E).  bf16 out.
// ---------------------------------------------------------------------------
__global__ void ygate_k(const float* __restrict__ ys, const __hip_bfloat16* __restrict__ xp,
                        __hip_bfloat16* __restrict__ y) {
    const int idx = blockIdx.x * blockDim.x + threadIdx.x;
    if (idx >= Mrows * Esz) return;
    const int e = idx & (Esz - 1);
    const size_t r = (size_t)(idx >> 11);
    const float g = __bfloat162float(xp[r * (2 * Esz) + Esz + e]);
    y[idx] = __float2bfloat16(ys[r] * g * sigmoidf_(g));
}

// ---------------------------------------------------------------------------
extern "C" void kernel_launch(void* const* d_in, const int* in_sizes, int n_in,
                              void* d_out, int out_size, void* d_ws, size_t ws_size,
                              hipStream_t stream) {
    const float* x      = (const float*)d_in[0];
    const float* in_w   = (const float*)d_in[1];
    const float* in_b   = (const float*)d_in[2];
    const float* conv_w = (const float*)d_in[3];
    const float* conv_b = (const float*)d_in[4];
    const float* dt_w   = (const float*)d_in[5];
    const float* dt_b   = (const float*)d_in[6];
    const float* B_w    = (const float*)d_in[7];
    const float* B_b    = (const float*)d_in[8];
    const float* C_w    = (const float*)d_in[9];
    const float* C_b    = (const float*)d_in[10];
    const float* D_w    = (const float*)d_in[11];
    const float* D_b    = (const float*)d_in[12];
    const float* out_w  = (const float*)d_in[13];
    const float* out_b  = (const float*)d_in[14];
    float* out = (float*)d_out;

    char* ws = (char*)d_ws;
    auto alloc = [&](size_t bytes) {
        char* p = ws;
        ws += (bytes + 255) & ~(size_t)255;
        return p;
    };
    __hip_bfloat16* x_bf    = (__hip_bfloat16*)alloc((size_t)Mrows * Dsz * 2);       // 16 MB
    __hip_bfloat16* inw_bf  = (__hip_bfloat16*)alloc((size_t)2 * Esz * Dsz * 2);     //  8 MB
    __hip_bfloat16* dtw_bf  = (__hip_bfloat16*)alloc((size_t)Esz * Esz * 2);         //  8 MB
    __hip_bfloat16* outw_bf = (__hip_bfloat16*)alloc((size_t)Dsz * Esz * 2);         //  4 MB
    __hip_bfloat16* xp_bf   = (__hip_bfloat16*)alloc((size_t)Mrows * 2 * Esz * 2);   // 64 MB
    __hip_bfloat16* xc_bf   = (__hip_bfloat16*)alloc((size_t)Mrows * Esz * 2);       // 32 MB
    __hip_bfloat16* wb_bf   = (__hip_bfloat16*)alloc((size_t)48 * Esz * 2);          // 192 KB
    float* rowsum = (float*)alloc(Mrows * 4);
    float* dec    = (float*)alloc(Mrows * 4);
    float* u_buf  = (float*)alloc((size_t)Mrows * Ssz * 4);
    float* ct_buf = (float*)alloc((size_t)Mrows * Ssz * 4);
    float* ys_buf = (float*)alloc(Mrows * 4);
    __hip_bfloat16* y_bf = xc_bf;   // reuse: xc dead after bcd/gemm<1>

    hipMemsetAsync(rowsum, 0, Mrows * 4, stream);

    // conversions (vectorized)
    f32_to_bf16v<<<2048, 256, 0, stream>>>((const float4*)x,     (ushort4*)x_bf,    Mrows * Dsz / 4);
    f32_to_bf16v<<<2048, 256, 0, stream>>>((const float4*)in_w,  (ushort4*)inw_bf,  2 * Esz * Dsz / 4);
    f32_to_bf16v<<<2048, 256, 0, stream>>>((const float4*)dt_w,  (ushort4*)dtw_bf,  Esz * Esz / 4);
    f32_to_bf16v<<<2048, 256, 0, stream>>>((const float4*)out_w, (ushort4*)outw_bf, Dsz * Esz / 4);
    pack_bcd<<<48 * Esz / 256, 256, 0, stream>>>(B_w, C_w, D_w, wb_bf);

    // GEMM1: xp = x @ in_w^T + in_b  (M=8192, N=4096, K=1024) -> bf16
    gemm_bt<0><<<dim3(4096 / 128, Mrows / 128), 256, 0, stream>>>(
        x_bf, inw_bf, in_b, Mrows, 4096, 1024, xp_bf, nullptr, nullptr, nullptr);

    // conv + SiLU -> xc
    conv_silu_k<<<(Mrows * Esz) / 256, 256, 0, stream>>>(xp_bf, conv_w, conv_b, xc_bf);

    // GEMM2: softplus(xc @ dt_w^T + dt_b) row-sums (M=8192, N=2048, K=2048)
    gemm_bt<1><<<dim3(Esz / 128, Mrows / 128), 256, 0, stream>>>(
        xc_bf, dtw_bf, dt_b, Mrows, Esz, Esz, nullptr, rowsum, nullptr, nullptr);

    decay_k<<<Mrows / 256, 256, 0, stream>>>(rowsum, dec);

    // B/C/D projections + u = Bt*Dt  (MFMA skinny GEMM)
    bcd_mfma<<<Mrows / 64, 256, 0, stream>>>(xc_bf, wb_bf, B_b, C_b, D_b, u_buf, ct_buf);

    // sequential scan -> ys
    scan_k<<<Bsz, 256, 0, stream>>>(dec, u_buf, ct_buf, ys_buf);

    // y = ys * silu(x_gate) -> bf16 (into xc buffer)
    ygate_k<<<(Mrows * Esz) / 256, 256, 0, stream>>>(ys_buf, xp_bf, y_bf);

    // GEMM3: out = x + y @ out_w^T + out_b  (M=8192, N=1024, K=2048) -> fp32
    gemm_bt<2><<<dim3(Dsz / 128, Mrows / 128), 256, 0, stream>>>(
        y_bf, outw_bf, out_b, Mrows, Dsz, Esz, nullptr, nullptr, x, out);
}

// Round 3
// 528.623 us; speedup vs baseline: 2.4784x; 1.1226x over previous
//
#include <hip/hip_runtime.h>
#include <hip/hip_bf16.h>

// Problem constants
#define Bsz 4
#define Tsz 2048
#define Dsz 1024
#define Ssz 16
#define Esz 2048
#define Mrows (Bsz*Tsz)        // 8192

typedef __attribute__((ext_vector_type(8))) short short8;
typedef __attribute__((ext_vector_type(4))) float floatx4;

__device__ __forceinline__ void async_ld16(const void* g, void* l) {
    __builtin_amdgcn_global_load_lds(
        (const __attribute__((address_space(1))) void*)g,
        (__attribute__((address_space(3))) void*)l,
        16, 0, 0);
}

__device__ __forceinline__ float sigmoidf_(float v) { return 1.f / (1.f + expf(-v)); }
__device__ __forceinline__ float bf2f(unsigned short u) {
    union { unsigned u32; float f; } c; c.u32 = (unsigned)u << 16; return c.f;
}

// ---------------------------------------------------------------------------
// merged fp32 -> bf16 conversion for x, in_w, dt_w, out_w (float4 granules)
// ---------------------------------------------------------------------------
#define CVT_S0 2097152   // x:     8388608 f32 / 4
#define CVT_S1 3145728   // in_w: +4194304 / 4
#define CVT_S2 4194304   // dt_w: +4194304 / 4
#define CVT_S3 4718592   // out_w:+2097152 / 4
__global__ void cvt_all(const float4* __restrict__ x,  const float4* __restrict__ iw,
                        const float4* __restrict__ dw, const float4* __restrict__ ow,
                        ushort4* __restrict__ xb,  ushort4* __restrict__ iwb,
                        ushort4* __restrict__ dwb, ushort4* __restrict__ owb) {
    int i = blockIdx.x * blockDim.x + threadIdx.x;
    const int stride = gridDim.x * blockDim.x;
    for (; i < CVT_S3; i += stride) {
        float4 v; ushort4* dst; int j;
        if (i < CVT_S0)      { v = x [j = i];           dst = xb  + j; }
        else if (i < CVT_S1) { v = iw[j = i - CVT_S0];  dst = iwb + j; }
        else if (i < CVT_S2) { v = dw[j = i - CVT_S1];  dst = dwb + j; }
        else                 { v = ow[j = i - CVT_S2];  dst = owb + j; }
        __hip_bfloat16 a = __float2bfloat16(v.x), b = __float2bfloat16(v.y);
        __hip_bfloat16 c = __float2bfloat16(v.z), d = __float2bfloat16(v.w);
        ushort4 o;
        o.x = *(unsigned short*)&a; o.y = *(unsigned short*)&b;
        o.z = *(unsigned short*)&c; o.w = *(unsigned short*)&d;
        *dst = o;
    }
}

// ---------------------------------------------------------------------------
// bf16 GEMM: C[M,N] = A[M,K] @ Bw[N,K]^T (+bias), 128x128 tile, 4 waves,
// 4x4 mfma_f32_16x16x32_bf16 per wave.  SOFTWARE-PIPELINED K-loop:
// double-buffered LDS, prefetch distance 2, raw s_barrier + vmcnt(4)
// (never vmcnt(0) inside the loop).  MODE: 0 bf16 store, 1 softplus rowsum,
// 2 fp32 + resid.
// ---------------------------------------------------------------------------
template<int MODE>
__launch_bounds__(256)
__global__ void gemm_bt(const __hip_bfloat16* __restrict__ A,
                        const __hip_bfloat16* __restrict__ Bw,
                        const float* __restrict__ bias,
                        int M, int N, int K,
                        __hip_bfloat16* __restrict__ outb,
                        float* __restrict__ rowsum,
                        const float* __restrict__ resid,
                        float* __restrict__ outf) {
    __shared__ __align__(16) __hip_bfloat16 sA[2 * 128 * 32];   // 16 KB
    __shared__ __align__(16) __hip_bfloat16 sB[2 * 128 * 32];   // 16 KB

    const int tid  = threadIdx.x;
    const int wave = tid >> 6, lane = tid & 63;
    const int wm = wave >> 1, wn = wave & 1;
    const int q = lane >> 4, lr = lane & 15;
    const int m0 = blockIdx.y * 128, n0 = blockIdx.x * 128;

    floatx4 acc[4][4];
#pragma unroll
    for (int i = 0; i < 4; ++i)
#pragma unroll
        for (int j = 0; j < 4; ++j) acc[i][j] = (floatx4){0.f, 0.f, 0.f, 0.f};

    // staging map: 512 chunks of 16B per 128x32 tile; thread -> 2 chunks each
    const int c0 = (wave * 2 + 0) * 64 + lane;
    const int c1 = (wave * 2 + 1) * 64 + lane;
    const int ra0 = c0 >> 2, ca0 = (c0 & 3) * 8;
    const int ra1 = c1 >> 2, ca1 = (c1 & 3) * 8;
    const int base0 = (wave * 2 + 0) * 512, base1 = (wave * 2 + 1) * 512;

    const __hip_bfloat16* pa0 = A  + (size_t)(m0 + ra0) * K + ca0;
    const __hip_bfloat16* pa1 = A  + (size_t)(m0 + ra1) * K + ca1;
    const __hip_bfloat16* pb0 = Bw + (size_t)(n0 + ra0) * K + ca0;
    const __hip_bfloat16* pb1 = Bw + (size_t)(n0 + ra1) * K + ca1;

    auto issue = [&](int koff, int cur) {
        const int o = cur * 4096;
        async_ld16(pa0 + koff, &sA[o + base0]);
        async_ld16(pa1 + koff, &sA[o + base1]);
        async_ld16(pb0 + koff, &sB[o + base0]);
        async_ld16(pb1 + koff, &sB[o + base1]);
    };

    const int nkt = K >> 5;
    issue(0, 0);          // tile 0 -> buf 0
    issue(32, 1);         // tile 1 -> buf 1
    int koff = 64;        // next tile to issue (clamped at tail)

    for (int kt = 0; kt < nkt; ++kt) {
        const int cur = kt & 1;
        // wait for tile kt only: tile kt+1's 4 loads stay in flight
        asm volatile("s_waitcnt vmcnt(4)" ::: "memory");
        asm volatile("s_barrier" ::: "memory");

        const __hip_bfloat16* sa = &sA[cur * 4096];
        const __hip_bfloat16* sb = &sB[cur * 4096];
        short8 af[4], bfr[4];
#pragma unroll
        for (int i = 0; i < 4; ++i)
            af[i] = *(const short8*)&sa[(wm * 64 + i * 16 + lr) * 32 + q * 8];
#pragma unroll
        for (int j = 0; j < 4; ++j)
            bfr[j] = *(const short8*)&sb[(wn * 64 + j * 16 + lr) * 32 + q * 8];

        // all frag reads landed -> safe for any wave to overwrite buf[cur]
        asm volatile("s_waitcnt lgkmcnt(0)" ::: "memory");
        asm volatile("s_barrier" ::: "memory");

        issue(koff, cur);                  // tile kt+2 (clamped) -> buf[cur]
        if (kt < nkt - 3) koff += 32;      // clamp keeps vmcnt accounting uniform

#pragma unroll
        for (int i = 0; i < 4; ++i)
#pragma unroll
            for (int j = 0; j < 4; ++j)
                acc[i][j] = __builtin_amdgcn_mfma_f32_16x16x32_bf16(af[i], bfr[j], acc[i][j], 0, 0, 0);
    }
    // drain tail DMA before LDS can be handed to the next workgroup
    asm volatile("s_waitcnt vmcnt(0)" ::: "memory");

    // epilogue: C/D layout col = lane&15, row = (lane>>4)*4 + reg
    if (MODE == 0) {
#pragma unroll
        for (int i = 0; i < 4; ++i) {
            const int row = m0 + wm * 64 + i * 16 + q * 4;
#pragma unroll
            for (int j = 0; j < 4; ++j) {
                const int col = n0 + wn * 64 + j * 16 + lr;
                const float bc = bias[col];
#pragma unroll
                for (int r = 0; r < 4; ++r)
                    outb[(size_t)(row + r) * N + col] = __float2bfloat16(acc[i][j][r] + bc);
            }
        }
    } else if (MODE == 1) {
#pragma unroll
        for (int i = 0; i < 4; ++i) {
            float rs[4] = {0.f, 0.f, 0.f, 0.f};
#pragma unroll
            for (int j = 0; j < 4; ++j) {
                const int col = n0 + wn * 64 + j * 16 + lr;
                const float bc = bias[col];
#pragma unroll
                for (int r = 0; r < 4; ++r) {
                    float v = acc[i][j][r] + bc;
                    float sp = (v > 20.f) ? v : log1pf(expf(v));
                    rs[r] += sp;
                }
            }
#pragma unroll
            for (int r = 0; r < 4; ++r) {
                float v = rs[r];
                v += __shfl_xor(v, 1); v += __shfl_xor(v, 2);
                v += __shfl_xor(v, 4); v += __shfl_xor(v, 8);
                if (lr == 0)
                    atomicAdd(&rowsum[m0 + wm * 64 + i * 16 + q * 4 + r], v);
            }
        }
    } else {
#pragma unroll
        for (int i = 0; i < 4; ++i) {
            const int row = m0 + wm * 64 + i * 16 + q * 4;
#pragma unroll
            for (int j = 0; j < 4; ++j) {
                const int col = n0 + wn * 64 + j * 16 + lr;
                const float bc = bias[col];
#pragma unroll
                for (int r = 0; r < 4; ++r) {
                    const size_t idx = (size_t)(row + r) * N + col;
                    outf[idx] = acc[i][j][r] + bc + resid[idx];
                }
            }
        }
    }
}

// ---------------------------------------------------------------------------
// depthwise conv (k=3, pad 1, along T) + bias + SiLU, 8 channels per thread.
// ---------------------------------------------------------------------------
__global__ void conv_silu_k(const __hip_bfloat16* __restrict__ xp,
                            const float* __restrict__ cw,
                            const float* __restrict__ cb,
                            __hip_bfloat16* __restrict__ xc) {
    const int idx8 = blockIdx.x * blockDim.x + threadIdx.x;  // Mrows*Esz/8 units
    const int e = (idx8 & (Esz / 8 - 1)) * 8;
    const int r = idx8 >> 8;           // Esz/8 = 256
    const int t = r & (Tsz - 1);
    const unsigned short* row0 = (const unsigned short*)(xp + (size_t)r * (2 * Esz) + e);
    short8 vm1 = (t > 0)       ? *(const short8*)(row0 - 2 * Esz) : (short8){0,0,0,0,0,0,0,0};
    short8 v00 = *(const short8*)row0;
    short8 vp1 = (t < Tsz - 1) ? *(const short8*)(row0 + 2 * Esz) : (short8){0,0,0,0,0,0,0,0};
    short8 o;
#pragma unroll
    for (int k = 0; k < 8; ++k) {
        const int ek = e + k;
        float v = bf2f((unsigned short)vm1[k]) * cw[ek * 3 + 0]
                + bf2f((unsigned short)v00[k]) * cw[ek * 3 + 1]
                + bf2f((unsigned short)vp1[k]) * cw[ek * 3 + 2] + cb[ek];
        __hip_bfloat16 h = __float2bfloat16(v * sigmoidf_(v));
        o[k] = *(short*)&h;
    }
    *(short8*)(xc + (size_t)idx8 * 8) = o;
}

// ---------------------------------------------------------------------------
// pack B_w/C_w/D_w (each [16,2048] fp32) into Wb [48,2048] bf16
// ---------------------------------------------------------------------------
__global__ void pack_bcd(const float* __restrict__ Bw, const float* __restrict__ Cw,
                         const float* __restrict__ Dw, __hip_bfloat16* __restrict__ Wb) {
    const int idx = blockIdx.x * blockDim.x + threadIdx.x;
    if (idx >= 48 * Esz) return;
    const int row = idx >> 11, col = idx & (Esz - 1);
    float v;
    if (row < 16)      v = Bw[row * Esz + col];
    else if (row < 32) v = Cw[(row - 16) * Esz + col];
    else               v = Dw[(row - 32) * Esz + col];
    Wb[idx] = __float2bfloat16(v);
}

// ---------------------------------------------------------------------------
// B/C/D projections via MFMA skinny GEMM: xc[M,E] @ Wb[48,E]^T.
// ---------------------------------------------------------------------------
__launch_bounds__(256)
__global__ void bcd_mfma(const __hip_bfloat16* __restrict__ xc,
                         const __hip_bfloat16* __restrict__ Wb,
                         const float* __restrict__ Bb, const float* __restrict__ Cb,
                         const float* __restrict__ Db,
                         float* __restrict__ u, float* __restrict__ Ct) {
    __shared__ __align__(16) __hip_bfloat16 sA[64 * 32];
    __shared__ __align__(16) __hip_bfloat16 sW[48 * 32];
    const int tid = threadIdx.x;
    const int wave = tid >> 6, lane = tid & 63;
    const int q = lane >> 4, lr = lane & 15;
    const int m0 = blockIdx.x * 64;

    floatx4 acc[3];
#pragma unroll
    for (int j = 0; j < 3; ++j) acc[j] = (floatx4){0.f, 0.f, 0.f, 0.f};

    const int ra = wave * 16 + (lane >> 2);
    const int ca = (lane & 3) * 8;

    for (int kt = 0; kt < (Esz >> 5); ++kt) {
        const int k0 = kt << 5;
        __syncthreads();
        async_ld16(&xc[(size_t)(m0 + ra) * Esz + k0 + ca], &sA[wave * 512]);
        if (wave < 3)
            async_ld16(&Wb[(size_t)ra * Esz + k0 + ca], &sW[wave * 512]);
        __syncthreads();

        short8 af = *(const short8*)&sA[(wave * 16 + lr) * 32 + q * 8];
#pragma unroll
        for (int j = 0; j < 3; ++j) {
            short8 wf = *(const short8*)&sW[(j * 16 + lr) * 32 + q * 8];
            acc[j] = __builtin_amdgcn_mfma_f32_16x16x32_bf16(af, wf, acc[j], 0, 0, 0);
        }
    }

    const int row = m0 + wave * 16 + q * 4;
    const float bb = Bb[lr], cbv = Cb[lr], db = Db[lr];
#pragma unroll
    for (int r = 0; r < 4; ++r) {
        const float bt = acc[0][r] + bb;
        const float ct = acc[1][r] + cbv;
        const float dt = acc[2][r] + db;
        u [(size_t)(row + r) * Ssz + lr] = bt * dt;
        Ct[(size_t)(row + r) * Ssz + lr] = ct;
    }
}

// ---------------------------------------------------------------------------
// Sequential SSM scan (decay computed inline from rowsum).  One block/batch.
// ---------------------------------------------------------------------------
__global__ void scan_k(const float* __restrict__ rowsum, const float* __restrict__ u,
                       const float* __restrict__ Ct, float* __restrict__ ys) {
    const int b = blockIdx.x;
    const int tid = threadIdx.x;
    const int lane = tid & 63, wave = tid >> 6;
    __shared__ __align__(16) float su[256 * Ssz];
    __shared__ __align__(16) float sc[256 * Ssz];
    __shared__ float sp[256 * 17];
    __shared__ float sd[256];
    float st = 0.f;
    for (int t0 = 0; t0 < Tsz; t0 += 256) {
        __syncthreads();
        const float4* ub = (const float4*)(u  + ((size_t)b * Tsz + t0) * Ssz);
        const float4* cb = (const float4*)(Ct + ((size_t)b * Tsz + t0) * Ssz);
#pragma unroll
        for (int i = 0; i < 4; ++i) {
            ((float4*)su)[tid + i * 256] = ub[tid + i * 256];
            ((float4*)sc)[tid + i * 256] = cb[tid + i * 256];
        }
        {
            const float m = rowsum[b * Tsz + t0 + tid] * (1.f / (float)Esz);
            sd[tid] = expf(fminf(fmaxf(-m, -10.f), 10.f));
        }
        __syncthreads();
        if (wave == 0 && lane < 16) {
#pragma unroll 8
            for (int i = 0; i < 256; ++i) {
                st = st * sd[i] + su[i * Ssz + lane];
                sp[i * 17 + lane] = sc[i * Ssz + lane] * st;
            }
        }
        __syncthreads();
        float s = 0.f;
#pragma unroll
        for (int j = 0; j < 16; ++j) s += sp[tid * 17 + j];
        ys[b * Tsz + t0 + tid] = s;
    }
}

// ---------------------------------------------------------------------------
// y[r,e] = ys[r] * silu(x_gate[r,e]), 8 per thread; gate = xp cols [E,2E).
// ---------------------------------------------------------------------------
__global__ void ygate_k(const float* __restrict__ ys, const __hip_bfloat16* __restrict__ xp,
                        __hip_bfloat16* __restrict__ y) {
    const int idx8 = blockIdx.x * blockDim.x + threadIdx.x;
    const int e = (idx8 & (Esz / 8 - 1)) * 8;
    const int r = idx8 >> 8;
    const float yr = ys[r];
    short8 g = *(const short8*)(xp + (size_t)r * (2 * Esz) + Esz + e);
    short8 o;
#pragma unroll
    for (int k = 0; k < 8; ++k) {
        const float gv = bf2f((unsigned short)g[k]);
        __hip_bfloat16 h = __float2bfloat16(yr * gv * sigmoidf_(gv));
        o[k] = *(short*)&h;
    }
    *(short8*)(y + (size_t)idx8 * 8) = o;
}

// ---------------------------------------------------------------------------
extern "C" void kernel_launch(void* const* d_in, const int* in_sizes, int n_in,
                              void* d_out, int out_size, void* d_ws, size_t ws_size,
                              hipStream_t stream) {
    const float* x      = (const float*)d_in[0];
    const float* in_w   = (const float*)d_in[1];
    const float* in_b   = (const float*)d_in[2];
    const float* conv_w = (const float*)d_in[3];
    const float* conv_b = (const float*)d_in[4];
    const float* dt_w   = (const float*)d_in[5];
    const float* dt_b   = (const float*)d_in[6];
    const float* B_w    = (const float*)d_in[7];
    const float* B_b    = (const float*)d_in[8];
    const float* C_w    = (const float*)d_in[9];
    const float* C_b    = (const float*)d_in[10];
    const float* D_w    = (const float*)d_in[11];
    const float* D_b    = (const float*)d_in[12];
    const float* out_w  = (const float*)d_in[13];
    const float* out_b  = (const float*)d_in[14];
    float* out = (float*)d_out;

    char* ws = (char*)d_ws;
    auto alloc = [&](size_t bytes) {
        char* p = ws;
        ws += (bytes + 255) & ~(size_t)255;
        return p;
    };
    __hip_bfloat16* x_bf    = (__hip_bfloat16*)alloc((size_t)Mrows * Dsz * 2);
    __hip_bfloat16* inw_bf  = (__hip_bfloat16*)alloc((size_t)2 * Esz * Dsz * 2);
    __hip_bfloat16* dtw_bf  = (__hip_bfloat16*)alloc((size_t)Esz * Esz * 2);
    __hip_bfloat16* outw_bf = (__hip_bfloat16*)alloc((size_t)Dsz * Esz * 2);
    __hip_bfloat16* xp_bf   = (__hip_bfloat16*)alloc((size_t)Mrows * 2 * Esz * 2);
    __hip_bfloat16* xc_bf   = (__hip_bfloat16*)alloc((size_t)Mrows * Esz * 2);
    __hip_bfloat16* wb_bf   = (__hip_bfloat16*)alloc((size_t)48 * Esz * 2);
    float* rowsum = (float*)alloc(Mrows * 4);
    float* u_buf  = (float*)alloc((size_t)Mrows * Ssz * 4);
    float* ct_buf = (float*)alloc((size_t)Mrows * Ssz * 4);
    float* ys_buf = (float*)alloc(Mrows * 4);
    __hip_bfloat16* y_bf = xc_bf;   // reuse: xc dead after bcd/gemm<1>

    hipMemsetAsync(rowsum, 0, Mrows * 4, stream);

    // conversions (single merged kernel)
    cvt_all<<<4608, 256, 0, stream>>>((const float4*)x, (const float4*)in_w,
                                      (const float4*)dt_w, (const float4*)out_w,
                                      (ushort4*)x_bf, (ushort4*)inw_bf,
                                      (ushort4*)dtw_bf, (ushort4*)outw_bf);
    pack_bcd<<<48 * Esz / 256, 256, 0, stream>>>(B_w, C_w, D_w, wb_bf);

    // GEMM1: xp = x @ in_w^T + in_b  (M=8192, N=4096, K=1024) -> bf16
    gemm_bt<0><<<dim3(4096 / 128, Mrows / 128), 256, 0, stream>>>(
        x_bf, inw_bf, in_b, Mrows, 4096, 1024, xp_bf, nullptr, nullptr, nullptr);

    // conv + SiLU -> xc
    conv_silu_k<<<(Mrows * Esz / 8) / 256, 256, 0, stream>>>(xp_bf, conv_w, conv_b, xc_bf);

    // GEMM2: softplus(xc @ dt_w^T + dt_b) row-sums (M=8192, N=2048, K=2048)
    gemm_bt<1><<<dim3(Esz / 128, Mrows / 128), 256, 0, stream>>>(
        xc_bf, dtw_bf, dt_b, Mrows, Esz, Esz, nullptr, rowsum, nullptr, nullptr);

    // B/C/D projections + u = Bt*Dt
    bcd_mfma<<<Mrows / 64, 256, 0, stream>>>(xc_bf, wb_bf, B_b, C_b, D_b, u_buf, ct_buf);

    // sequential scan (decay inline) -> ys
    scan_k<<<Bsz, 256, 0, stream>>>(rowsum, u_buf, ct_buf, ys_buf);

    // y = ys * silu(x_gate) -> bf16 (into xc buffer)
    ygate_k<<<(Mrows * Esz / 8) / 256, 256, 0, stream>>>(ys_buf, xp_bf, y_bf);

    // GEMM3: out = x + y @ out_w^T + out_b  (M=8192, N=1024, K=2048) -> fp32
    gemm_bt<2><<<dim3(Dsz / 128, Mrows / 128), 256, 0, stream>>>(
        y_bf, outw_bf, out_b, Mrows, Dsz, Esz, nullptr, nullptr, x, out);
}